// Round 1
// 352.009 us; speedup vs baseline: 1.0423x; 1.0423x over previous
//
#include <hip/hip_runtime.h>
#include <hip/hip_bf16.h>

// B=4, N=256, F=64, H=256, A=16, T=3.  BN=1024 rows.
// bf16 inputs (runtime-verified); adjacency int32.
// GEMMs: bf16 MFMA 16x16x32. Weights are EXACT in bf16 (inputs are bf16).
// Precision: activations h/Ehat stored as split hi/lo bf16 pairs along K,
// weights duplicated along K -> A_hi@B + A_lo@B in one MFMA GEMM (~fp32 acc).
// R1: agg∘gi fused via precomputed Wg = W2hat·Wih (3-term split-K, K=864);
//     all GEMMs moved to 64x128 tiles for 2x grid spread (latency-bound).

typedef unsigned short ushort_t;
typedef short bf8_t __attribute__((ext_vector_type(8)));
typedef float f4_t  __attribute__((ext_vector_type(4)));

#define BN_ROWS 1024

// ---- bf16 regions (USHORT offsets) ----
#define UB_NFB    0         // 65536   NF [1024][64] (exact)
#define UB_PW1T   65536     // 16384   preW1^T [256][64]
#define UB_PW2T   81920     // 65536   preW2^T [256][256]
#define UB_WCATT  147456    // 655360  Wcat^T dup [1280][512]
#define UB_WGT    802816    // 663552  Wg^T [768][864] = [hi(288)|hi(288)|lo(288)]
#define UB_XB     1466368   // 262144  X [1024][256] single bf16
#define UB_H2     1728512   // 524288  h  [1024][512] hi|lo
#define UB_EHAT2  2252800   // 884736  Ehat [1024][864] hi(288)|lo(288)|hi(288)
#define UB_END    3137536   // -> 1568768 floats

// ---- fp32 regions (FLOAT offsets), contiguous from F_PREB1 ----
#define F_PREB1   1568768   // 256
#define F_PREB2   1569024   // 256
#define F_BCAT    1569280   // 1280  [msg_b1 | 0 | gru_bhh]
#define F_BIH     1570560   // 768
#define F_ROW1    1571328   // 65536
#define F_ROB1    1636864   // 256
#define F_ROW2    1637120   // 4096
#define F_ROB2    1641216   // 16
#define F_H       1641232   // 262144
#define F_HCAT    1903376   // 1310720 [hi_p | hj | gh]
#define F_GI      3214096   // 786432
#define F_FLAG    4000528   // 1 int        (total ~16.0 MiB)

// ---- convert index space ----
#define CVa 65536     // end NFB
#define CVb 81920     // end PW1T
#define CVc 147456    // end PW2T
#define CVd 802816    // end WCATT
#define CV_TOTAL 875280   // + 72464 fp32 tail

__device__ __forceinline__ float bf2f(ushort_t u) {
    return __uint_as_float(((unsigned int)u) << 16);
}
__device__ __forceinline__ ushort_t f2b(float v) {
    __hip_bfloat16 b = __float2bfloat16(v);
    return *reinterpret_cast<ushort_t*>(&b);
}
__device__ __forceinline__ float relu(float v) { return v < 0.f ? 0.f : v; }  // NaN-propagating
__device__ __forceinline__ float ld(const void* p, int i, int isf32) {
    return isf32 ? ((const float*)p)[i] : bf2f(((const ushort_t*)p)[i]);
}

__global__ __launch_bounds__(256) void detect_kernel(const ushort_t* __restrict__ nf,
                                                     int* __restrict__ flag) {
    __shared__ int cnt;
    if (threadIdx.x == 0) cnt = 0;
    __syncthreads();
    int bad = 0;
    for (int i = 0; i < 8; ++i) {
        ushort_t u = nf[(threadIdx.x * 8 + i) * 2];
        int ex = (u >> 7) & 0xFF;
        if ((u & 0x7fff) != 0 && (ex < 100 || ex > 140)) bad++;
    }
    atomicAdd(&cnt, bad);
    __syncthreads();
    if (threadIdx.x == 0) *flag = (cnt > 512) ? 1 : 0;
}

__global__ __launch_bounds__(256) void convert_kernel(
    const void* nf, const void* preW1, const void* preb1, const void* preW2, const void* preb2,
    const void* msgW1, const void* msgb1, const void* msgW2, const void* msgb2,
    const void* gruWih, const void* gruWhh, const void* grubih, const void* grubhh,
    const void* roW1, const void* rob1, const void* roW2, const void* rob2,
    float* __restrict__ w, const int* __restrict__ flagp)
{
    int e = blockIdx.x * 256 + threadIdx.x;
    if (e >= CV_TOTAL) return;
    const int f32 = *flagp;
    ushort_t* wb = (ushort_t*)w;
    if (e < CVa) {                                    // NF
        wb[UB_NFB + e] = f2b(ld(nf, e, f32));
    } else if (e < CVb) {                             // preW1^T [256][64]
        int i = e - CVa; int n = i >> 6, k = i & 63;
        wb[UB_PW1T + i] = f2b(ld(preW1, k * 256 + n, f32));
    } else if (e < CVc) {                             // preW2^T [256][256]
        int i = e - CVb; int n = i >> 8, k = i & 255;
        wb[UB_PW2T + i] = f2b(ld(preW2, k * 256 + n, f32));
    } else if (e < CVd) {                             // Wcat^T dup [1280][512]
        int i = e - CVc; int n = i >> 9, k = (i & 511) & 255;
        float v;
        if (n < 256)      v = ld(msgW1, k * 256 + n, f32);
        else if (n < 512) v = ld(msgW1, (256 + k) * 256 + (n - 256), f32);
        else              v = ld(gruWhh, k * 768 + (n - 512), f32);
        wb[UB_WCATT + i] = f2b(v);
    } else {                                          // fp32 tail (contiguous)
        int f = e - CVd;
        float v;
        if (f < 256)        v = ld(preb1, f, f32);
        else if (f < 512)   v = ld(preb2, f - 256, f32);
        else if (f < 1792) {
            int c = f - 512;
            if (c < 256)      v = ld(msgb1, c, f32);
            else if (c < 512) v = 0.f;
            else              v = ld(grubhh, c - 512, f32);
        }
        else if (f < 2560)  v = ld(grubih, f - 1792, f32);
        else if (f < 68096) v = ld(roW1, f - 2560, f32);
        else if (f < 68352) v = ld(rob1, f - 68096, f32);
        else if (f < 72448) v = ld(roW2, f - 68352, f32);
        else                v = ld(rob2, f - 72448, f32);
        w[F_PREB1 + f] = v;
    }
}

// Wg[k][p] = sum_n W2hat[k][n] * Wih[n][p],  k in [0,288), p in [0,768)
//   W2hat[k][n] = msgW2[k][n] (k<256) | msgb2[n] (k==256) | 0 (k>256).
// Written transposed+tripled for mgemm B operand: WgT[p][864] = [hi|hi|lo].
// Pairing with Ehat = [Eh|El|Eh]: Eh*Wg_hi + El*Wg_hi + Eh*Wg_lo (El*Wg_lo ~2^-18, dropped).
__global__ __launch_bounds__(256) void wg_kernel(
    const void* msgW2, const void* msgb2, const void* gruWih,
    ushort_t* __restrict__ wgt, const int* __restrict__ flagp)
{
    __shared__ float w2s[16 * 256];
    const int f32 = *flagp;
    const int t = threadIdx.x;
    const int p0 = blockIdx.x * 256;
    const int k0 = blockIdx.y * 16;
    for (int i = t; i < 16 * 256; i += 256) {
        int r = i >> 8, n = i & 255;
        int krow = k0 + r;
        float v;
        if (krow < 256)       v = ld(msgW2, krow * 256 + n, f32);
        else if (krow == 256) v = ld(msgb2, n, f32);
        else                  v = 0.f;
        w2s[i] = v;
    }
    __syncthreads();
    const int p = p0 + t;
    float acc[16] = {};
    for (int n = 0; n < 256; ++n) {
        float wv = ld(gruWih, n * 768 + p, f32);
#pragma unroll
        for (int r = 0; r < 16; ++r) acc[r] += w2s[r * 256 + n] * wv;
    }
#pragma unroll
    for (int r = 0; r < 16; ++r) {
        int krow = k0 + r;
        ushort_t hi = f2b(acc[r]);
        ushort_t lo = f2b(acc[r] - bf2f(hi));
        wgt[p * 864 + krow] = hi;
        wgt[p * 864 + 288 + krow] = hi;
        wgt[p * 864 + 576 + krow] = lo;
    }
}

// bf16 MFMA GEMM: C[M,N] = A[M,K] @ Bt[N,K]^T (+bias) (+relu).
// C (fp32) optional; Cb (bf16) optional with row stride cbld; if cblo!=0 also
// writes lo residual at col offset cblo (split hi/lo output).
// Block tile BM x 128 (BM in {64,128}), 4 waves. M%BM==0; N%128==0; K%32==0.
template<int BM>
__global__ __launch_bounds__(256) void mgemm_k(
    const ushort_t* __restrict__ A,
    const ushort_t* __restrict__ Bt,
    const float* __restrict__ bias,
    float* __restrict__ C,
    ushort_t* __restrict__ Cb, int cbld, int cblo,
    int K, int N, int dorelu)
{
    constexpr int MR = BM / 32;                 // 16-row frags per wave (M dir)
    __shared__ ushort_t As[BM * 32];
    __shared__ ushort_t Bs[128 * 32];
    const int t = threadIdx.x;
    const int wave = t >> 6, lane = t & 63;
    const int ln = lane & 15, quad = lane >> 4;
    const int bm = blockIdx.y * BM, bn = blockIdx.x * 128;
    const int wm = (wave >> 1) * (BM / 2), wn = (wave & 1) * 64;
    const int srow = t >> 2, skc = (t & 3) << 3;

    f4_t acc[MR][4] = {};

    for (int k0 = 0; k0 < K; k0 += 32) {
        __syncthreads();
#pragma unroll
        for (int r = 0; r < BM / 64; ++r) {
            int row = srow + r * 64;
            *(bf8_t*)(&As[row * 32 + skc]) = *(const bf8_t*)(&A[(bm + row) * K + k0 + skc]);
        }
#pragma unroll
        for (int r = 0; r < 2; ++r) {
            int row = srow + r * 64;
            *(bf8_t*)(&Bs[row * 32 + skc]) = *(const bf8_t*)(&Bt[(bn + row) * K + k0 + skc]);
        }
        __syncthreads();
        bf8_t af[MR], bfr[4];
#pragma unroll
        for (int i = 0; i < MR; ++i)
            af[i]  = *(const bf8_t*)(&As[(wm + i * 16 + ln) * 32 + quad * 8]);
#pragma unroll
        for (int i = 0; i < 4; ++i)
            bfr[i] = *(const bf8_t*)(&Bs[(wn + i * 16 + ln) * 32 + quad * 8]);
#pragma unroll
        for (int mi = 0; mi < MR; ++mi)
#pragma unroll
            for (int ni = 0; ni < 4; ++ni)
                acc[mi][ni] = __builtin_amdgcn_mfma_f32_16x16x32_bf16(
                    af[mi], bfr[ni], acc[mi][ni], 0, 0, 0);
    }

#pragma unroll
    for (int mi = 0; mi < MR; ++mi) {
#pragma unroll
        for (int ni = 0; ni < 4; ++ni) {
            int col = bn + wn + ni * 16 + ln;
            float bb = bias ? bias[col] : 0.f;
#pragma unroll
            for (int r = 0; r < 4; ++r) {
                int row = bm + wm + mi * 16 + quad * 4 + r;
                float v = acc[mi][ni][r] + bb;
                if (dorelu) v = relu(v);
                if (C) C[row * N + col] = v;
                if (Cb) {
                    ushort_t hi = f2b(v);
                    Cb[row * cbld + col] = hi;
                    if (cblo) Cb[row * cbld + cblo + col] = f2b(v - bf2f(hi));
                }
            }
        }
    }
}

// Ehat[row] (width 864): [ sum_{j:adj=1} relu(hi_p+hj) hi (256) | deg | 0 |
//                          same lo (256) | 0 | same hi again (256) | deg | 0 ]
__global__ __launch_bounds__(256) void msg_kernel(
    const float* __restrict__ hcat,   // [1024][1280]: [hi_p | hj | gh]
    const int*   __restrict__ adj,    // [1024][256]
    ushort_t* __restrict__ ehat)      // [1024][864]
{
    const int row = blockIdx.x;
    const int t = threadIdx.x;
    __shared__ int ej[256];
    __shared__ int ecnt;
    if (t == 0) ecnt = 0;
    __syncthreads();
    if (adj[row * 256 + t]) { int p = atomicAdd(&ecnt, 1); ej[p] = t; }
    const float hi = hcat[row * 1280 + t];
    const float* hjb = hcat + (row >> 8) * 256 * 1280 + 256;
    __syncthreads();
    const int ne = ecnt;
    float acc = 0.f;
#pragma unroll 4
    for (int p = 0; p < ne; ++p) {
        int j = ej[p];
        acc += relu(hi + hjb[j * 1280 + t]);
    }
    ushort_t h16 = f2b(acc);
    ushort_t l16 = f2b(acc - bf2f(h16));
    ehat[row * 864 + t] = h16;
    ehat[row * 864 + 288 + t] = l16;
    ehat[row * 864 + 576 + t] = h16;
    if (t < 32) {
        ushort_t d = f2b(t == 0 ? (float)ne : 0.f);  // deg exact (<=256)
        ehat[row * 864 + 256 + t] = d;
        ehat[row * 864 + 544 + t] = 0;
        ehat[row * 864 + 832 + t] = d;
    }
}

__global__ __launch_bounds__(256) void gru_kernel(
    const float* __restrict__ gi,     // [1024][768]
    const float* __restrict__ hcat,   // gh at col 512
    float* __restrict__ h,            // fp32 h (in/out)
    ushort_t* __restrict__ h2)        // bf16 h hi|lo [1024][512]
{
    const int row = blockIdx.x;
    const int t = threadIdx.x;
    const float* gir = gi + row * 768;
    const float* ghr = hcat + row * 1280 + 512;
    float ir = gir[t], iz = gir[256 + t], in = gir[512 + t];
    float hr = ghr[t], hz = ghr[256 + t], hn = ghr[512 + t];
    float r = 1.f / (1.f + __expf(-(ir + hr)));
    float z = 1.f / (1.f + __expf(-(iz + hz)));
    float n = tanhf(in + r * hn);
    float ho = h[row * 256 + t];
    float hv = (1.f - z) * n + z * ho;
    h[row * 256 + t] = hv;
    ushort_t hb = f2b(hv);
    h2[row * 512 + t] = hb;
    h2[row * 512 + 256 + t] = f2b(hv - bf2f(hb));
}

__global__ __launch_bounds__(256) void readout_kernel(
    const float* __restrict__ h,
    const float* __restrict__ roW1, const float* __restrict__ rob1,
    const float* __restrict__ roW2, const float* __restrict__ rob2,
    void* __restrict__ out, const int* __restrict__ flagp)
{
    const int b = blockIdx.x;
    const int t = threadIdx.x;
    __shared__ float gl[256], t1[256];
    const float* hb = h + b * 256 * 256;
    float s = 0.f;
    for (int n = 0; n < 256; ++n) s += hb[n * 256 + t];
    gl[t] = s;
    __syncthreads();
    float acc = rob1[t];
    for (int k = 0; k < 256; ++k) acc += gl[k] * roW1[k * 256 + t];
    t1[t] = relu(acc);
    __syncthreads();
    if (t < 16) {
        float q = rob2[t];
        for (int k = 0; k < 256; ++k) q += t1[k] * roW2[k * 16 + t];
        if (*flagp) ((float*)out)[b * 16 + t] = q;
        else ((__hip_bfloat16*)out)[b * 16 + t] = __float2bfloat16(q);
    }
}

extern "C" void kernel_launch(void* const* d_in, const int* in_sizes, int n_in,
                              void* d_out, int out_size, void* d_ws, size_t ws_size,
                              hipStream_t stream) {
    float* w = (float*)d_ws;
    ushort_t* wb = (ushort_t*)d_ws;
    int* flagp = (int*)(w + F_FLAG);

    static const int dictSz[18]  = {65536,262144,16384,256,65536,256,131072,256,65536,256,
                                    196608,196608,768,768,65536,256,4096,16};
    static const int alphaSz[18] = {262144,196608,196608,768,768,131072,65536,256,256,
                                    65536,16384,65536,256,256,65536,4096,256,16};
    static const int alphaPos[18] = {9,0,10,12,11,13,5,7,6,8,2,1,4,3,14,16,15,17};
    bool dictOK = true, alphaOK = true;
    for (int i = 0; i < 18 && i < n_in; ++i) {
        if (in_sizes[i] != dictSz[i])  dictOK = false;
        if (in_sizes[i] != alphaSz[i]) alphaOK = false;
    }
    const void* P[18];
    for (int l = 0; l < 18; ++l) P[l] = d_in[(!dictOK && alphaOK) ? alphaPos[l] : l];
    const int* adj = (const int*)P[1];

    detect_kernel<<<1, 256, 0, stream>>>((const ushort_t*)P[0], flagp);
    convert_kernel<<<(CV_TOTAL + 255) / 256, 256, 0, stream>>>(
        P[0], P[2], P[3], P[4], P[5], P[6], P[7], P[8], P[9],
        P[10], P[11], P[12], P[13], P[14], P[15], P[16], P[17], w, flagp);
    // Wg = W2hat . Wih  (fp32 accumulate over exact-bf16 weights, split hi/lo)
    wg_kernel<<<dim3(3, 18), 256, 0, stream>>>(P[8], P[9], P[10], wb + UB_WGT, flagp);

    // pre-net: X = relu(NF@preW1+b1) -> bf16 single; h = X@preW2+b2 -> fp32 + hi/lo
    mgemm_k<64><<<dim3(2, 16), 256, 0, stream>>>(
        wb + UB_NFB, wb + UB_PW1T, w + F_PREB1, (float*)nullptr,
        wb + UB_XB, 256, 0, 64, 256, 1);
    mgemm_k<64><<<dim3(2, 16), 256, 0, stream>>>(
        wb + UB_XB, wb + UB_PW2T, w + F_PREB2, w + F_H,
        wb + UB_H2, 512, 256, 256, 256, 0);

    for (int it = 0; it < 3; ++it) {
        // hcat = h @ [W1_i|W1_j|Whh] + [b1|0|bhh]   (A = h hi|lo, K=512)
        mgemm_k<64><<<dim3(10, 16), 256, 0, stream>>>(
            wb + UB_H2, wb + UB_WCATT, w + F_BCAT, w + F_HCAT,
            (ushort_t*)nullptr, 0, 0, 512, 1280, 0);
        msg_kernel<<<BN_ROWS, 256, 0, stream>>>(w + F_HCAT, adj, wb + UB_EHAT2);
        // gi = Ehat @ Wg + bih  (A = Ehat [Eh|El|Eh], K=864; deg col folds msg_b2)
        mgemm_k<64><<<dim3(6, 16), 256, 0, stream>>>(
            wb + UB_EHAT2, wb + UB_WGT, w + F_BIH, w + F_GI,
            (ushort_t*)nullptr, 0, 0, 864, 768, 0);
        gru_kernel<<<BN_ROWS, 256, 0, stream>>>(w + F_GI, w + F_HCAT,
                                                w + F_H, wb + UB_H2);
    }

    readout_kernel<<<4, 256, 0, stream>>>(w + F_H, w + F_ROW1, w + F_ROB1,
                                          w + F_ROW2, w + F_ROB2, d_out, flagp);
}

// Round 2
// 311.235 us; speedup vs baseline: 1.1788x; 1.1310x over previous
//
#include <hip/hip_runtime.h>
#include <hip/hip_bf16.h>

// B=4, N=256, F=64, H=256, A=16, T=3.  BN=1024 rows.
// bf16 inputs (runtime-verified); adjacency int32.
// GEMMs: bf16 MFMA 16x16x32. Weights are EXACT in bf16 (inputs are bf16).
// Precision: activations h/Ehat stored as split hi/lo bf16 pairs along K,
// weights duplicated along K -> A_hi@B + A_lo@B in one MFMA GEMM (~fp32 acc).
// R1: agg∘gi fused via precomputed Wg = W2hat·Wih (3-term split-K, K=864);
//     all GEMMs moved to 64x128 tiles for 2x grid spread (latency-bound).
// R2: wg_kernel was 60us latency-bound (VALUBusy 1.7%, 0.2 waves/SIMD,
//     256 serial loads/thread). Reworked: 32-wide register load batches,
//     k-tile 16->4 (216 blocks), float4 LDS reads. Target ~5us.

typedef unsigned short ushort_t;
typedef short bf8_t __attribute__((ext_vector_type(8)));
typedef float f4_t  __attribute__((ext_vector_type(4)));

#define BN_ROWS 1024

// ---- bf16 regions (USHORT offsets) ----
#define UB_NFB    0         // 65536   NF [1024][64] (exact)
#define UB_PW1T   65536     // 16384   preW1^T [256][64]
#define UB_PW2T   81920     // 65536   preW2^T [256][256]
#define UB_WCATT  147456    // 655360  Wcat^T dup [1280][512]
#define UB_WGT    802816    // 663552  Wg^T [768][864] = [hi(288)|hi(288)|lo(288)]
#define UB_XB     1466368   // 262144  X [1024][256] single bf16
#define UB_H2     1728512   // 524288  h  [1024][512] hi|lo
#define UB_EHAT2  2252800   // 884736  Ehat [1024][864] hi(288)|lo(288)|hi(288)
#define UB_END    3137536   // -> 1568768 floats

// ---- fp32 regions (FLOAT offsets), contiguous from F_PREB1 ----
#define F_PREB1   1568768   // 256
#define F_PREB2   1569024   // 256
#define F_BCAT    1569280   // 1280  [msg_b1 | 0 | gru_bhh]
#define F_BIH     1570560   // 768
#define F_ROW1    1571328   // 65536
#define F_ROB1    1636864   // 256
#define F_ROW2    1637120   // 4096
#define F_ROB2    1641216   // 16
#define F_H       1641232   // 262144
#define F_HCAT    1903376   // 1310720 [hi_p | hj | gh]
#define F_GI      3214096   // 786432
#define F_FLAG    4000528   // 1 int        (total ~16.0 MiB)

// ---- convert index space ----
#define CVa 65536     // end NFB
#define CVb 81920     // end PW1T
#define CVc 147456    // end PW2T
#define CVd 802816    // end WCATT
#define CV_TOTAL 875280   // + 72464 fp32 tail

__device__ __forceinline__ float bf2f(ushort_t u) {
    return __uint_as_float(((unsigned int)u) << 16);
}
__device__ __forceinline__ ushort_t f2b(float v) {
    __hip_bfloat16 b = __float2bfloat16(v);
    return *reinterpret_cast<ushort_t*>(&b);
}
__device__ __forceinline__ float relu(float v) { return v < 0.f ? 0.f : v; }  // NaN-propagating
__device__ __forceinline__ float ld(const void* p, int i, int isf32) {
    return isf32 ? ((const float*)p)[i] : bf2f(((const ushort_t*)p)[i]);
}

__global__ __launch_bounds__(256) void detect_kernel(const ushort_t* __restrict__ nf,
                                                     int* __restrict__ flag) {
    __shared__ int cnt;
    if (threadIdx.x == 0) cnt = 0;
    __syncthreads();
    int bad = 0;
    for (int i = 0; i < 8; ++i) {
        ushort_t u = nf[(threadIdx.x * 8 + i) * 2];
        int ex = (u >> 7) & 0xFF;
        if ((u & 0x7fff) != 0 && (ex < 100 || ex > 140)) bad++;
    }
    atomicAdd(&cnt, bad);
    __syncthreads();
    if (threadIdx.x == 0) *flag = (cnt > 512) ? 1 : 0;
}

__global__ __launch_bounds__(256) void convert_kernel(
    const void* nf, const void* preW1, const void* preb1, const void* preW2, const void* preb2,
    const void* msgW1, const void* msgb1, const void* msgW2, const void* msgb2,
    const void* gruWih, const void* gruWhh, const void* grubih, const void* grubhh,
    const void* roW1, const void* rob1, const void* roW2, const void* rob2,
    float* __restrict__ w, const int* __restrict__ flagp)
{
    int e = blockIdx.x * 256 + threadIdx.x;
    if (e >= CV_TOTAL) return;
    const int f32 = *flagp;
    ushort_t* wb = (ushort_t*)w;
    if (e < CVa) {                                    // NF
        wb[UB_NFB + e] = f2b(ld(nf, e, f32));
    } else if (e < CVb) {                             // preW1^T [256][64]
        int i = e - CVa; int n = i >> 6, k = i & 63;
        wb[UB_PW1T + i] = f2b(ld(preW1, k * 256 + n, f32));
    } else if (e < CVc) {                             // preW2^T [256][256]
        int i = e - CVb; int n = i >> 8, k = i & 255;
        wb[UB_PW2T + i] = f2b(ld(preW2, k * 256 + n, f32));
    } else if (e < CVd) {                             // Wcat^T dup [1280][512]
        int i = e - CVc; int n = i >> 9, k = (i & 511) & 255;
        float v;
        if (n < 256)      v = ld(msgW1, k * 256 + n, f32);
        else if (n < 512) v = ld(msgW1, (256 + k) * 256 + (n - 256), f32);
        else              v = ld(gruWhh, k * 768 + (n - 512), f32);
        wb[UB_WCATT + i] = f2b(v);
    } else {                                          // fp32 tail (contiguous)
        int f = e - CVd;
        float v;
        if (f < 256)        v = ld(preb1, f, f32);
        else if (f < 512)   v = ld(preb2, f - 256, f32);
        else if (f < 1792) {
            int c = f - 512;
            if (c < 256)      v = ld(msgb1, c, f32);
            else if (c < 512) v = 0.f;
            else              v = ld(grubhh, c - 512, f32);
        }
        else if (f < 2560)  v = ld(grubih, f - 1792, f32);
        else if (f < 68096) v = ld(roW1, f - 2560, f32);
        else if (f < 68352) v = ld(rob1, f - 68096, f32);
        else if (f < 72448) v = ld(roW2, f - 68352, f32);
        else                v = ld(rob2, f - 72448, f32);
        w[F_PREB1 + f] = v;
    }
}

// Wg[k][p] = sum_n W2hat[k][n] * Wih[n][p],  k in [0,288), p in [0,768)
//   W2hat[k][n] = msgW2[k][n] (k<256) | msgb2[n] (k==256) | 0 (k>256).
// Written transposed+tripled for mgemm B operand: WgT[p][864] = [hi|hi|lo].
// Pairing with Ehat = [Eh|El|Eh]: Eh*Wg_hi + El*Wg_hi + Eh*Wg_lo (El*Wg_lo ~2^-18, dropped).
// R2 layout: block = (p-tile 256) x (k-tile 4); 216 blocks.
// Loads batched 32-wide into registers (independent, pipelined); W2hat tile
// staged once in LDS, read as float4 (uniform broadcast).
__global__ __launch_bounds__(256) void wg_kernel(
    const void* msgW2, const void* msgb2, const void* gruWih,
    ushort_t* __restrict__ wgt, const int* __restrict__ flagp)
{
    __shared__ float w2s[4 * 256];
    const int f32 = *flagp;
    const int t = threadIdx.x;
    const int p0 = blockIdx.x * 256;
    const int k0 = blockIdx.y * 4;
    // stage W2hat rows k0..k0+3 (4x256 = 4 elems/thread)
    for (int i = t; i < 4 * 256; i += 256) {
        int r = i >> 8, n = i & 255;
        int krow = k0 + r;
        float v;
        if (krow < 256)       v = ld(msgW2, krow * 256 + n, f32);
        else if (krow == 256) v = ld(msgb2, n, f32);
        else                  v = 0.f;
        w2s[i] = v;
    }
    __syncthreads();
    const int p = p0 + t;
    float acc[4] = {};
    for (int n0 = 0; n0 < 256; n0 += 32) {
        float wv[32];
#pragma unroll
        for (int i = 0; i < 32; ++i)               // 32 independent loads in flight
            wv[i] = ld(gruWih, (n0 + i) * 768 + p, f32);
#pragma unroll
        for (int r = 0; r < 4; ++r) {
            float a = acc[r];
#pragma unroll
            for (int q = 0; q < 8; ++q) {
                f4_t w4 = *(const f4_t*)&w2s[r * 256 + n0 + q * 4];
                a += w4[0] * wv[q * 4 + 0] + w4[1] * wv[q * 4 + 1]
                   + w4[2] * wv[q * 4 + 2] + w4[3] * wv[q * 4 + 3];
            }
            acc[r] = a;
        }
    }
#pragma unroll
    for (int r = 0; r < 4; ++r) {
        int krow = k0 + r;
        ushort_t hi = f2b(acc[r]);
        ushort_t lo = f2b(acc[r] - bf2f(hi));
        wgt[p * 864 + krow] = hi;
        wgt[p * 864 + 288 + krow] = hi;
        wgt[p * 864 + 576 + krow] = lo;
    }
}

// bf16 MFMA GEMM: C[M,N] = A[M,K] @ Bt[N,K]^T (+bias) (+relu).
// C (fp32) optional; Cb (bf16) optional with row stride cbld; if cblo!=0 also
// writes lo residual at col offset cblo (split hi/lo output).
// Block tile BM x 128 (BM in {64,128}), 4 waves. M%BM==0; N%128==0; K%32==0.
template<int BM>
__global__ __launch_bounds__(256) void mgemm_k(
    const ushort_t* __restrict__ A,
    const ushort_t* __restrict__ Bt,
    const float* __restrict__ bias,
    float* __restrict__ C,
    ushort_t* __restrict__ Cb, int cbld, int cblo,
    int K, int N, int dorelu)
{
    constexpr int MR = BM / 32;                 // 16-row frags per wave (M dir)
    __shared__ ushort_t As[BM * 32];
    __shared__ ushort_t Bs[128 * 32];
    const int t = threadIdx.x;
    const int wave = t >> 6, lane = t & 63;
    const int ln = lane & 15, quad = lane >> 4;
    const int bm = blockIdx.y * BM, bn = blockIdx.x * 128;
    const int wm = (wave >> 1) * (BM / 2), wn = (wave & 1) * 64;
    const int srow = t >> 2, skc = (t & 3) << 3;

    f4_t acc[MR][4] = {};

    for (int k0 = 0; k0 < K; k0 += 32) {
        __syncthreads();
#pragma unroll
        for (int r = 0; r < BM / 64; ++r) {
            int row = srow + r * 64;
            *(bf8_t*)(&As[row * 32 + skc]) = *(const bf8_t*)(&A[(bm + row) * K + k0 + skc]);
        }
#pragma unroll
        for (int r = 0; r < 2; ++r) {
            int row = srow + r * 64;
            *(bf8_t*)(&Bs[row * 32 + skc]) = *(const bf8_t*)(&Bt[(bn + row) * K + k0 + skc]);
        }
        __syncthreads();
        bf8_t af[MR], bfr[4];
#pragma unroll
        for (int i = 0; i < MR; ++i)
            af[i]  = *(const bf8_t*)(&As[(wm + i * 16 + ln) * 32 + quad * 8]);
#pragma unroll
        for (int i = 0; i < 4; ++i)
            bfr[i] = *(const bf8_t*)(&Bs[(wn + i * 16 + ln) * 32 + quad * 8]);
#pragma unroll
        for (int mi = 0; mi < MR; ++mi)
#pragma unroll
            for (int ni = 0; ni < 4; ++ni)
                acc[mi][ni] = __builtin_amdgcn_mfma_f32_16x16x32_bf16(
                    af[mi], bfr[ni], acc[mi][ni], 0, 0, 0);
    }

#pragma unroll
    for (int mi = 0; mi < MR; ++mi) {
#pragma unroll
        for (int ni = 0; ni < 4; ++ni) {
            int col = bn + wn + ni * 16 + ln;
            float bb = bias ? bias[col] : 0.f;
#pragma unroll
            for (int r = 0; r < 4; ++r) {
                int row = bm + wm + mi * 16 + quad * 4 + r;
                float v = acc[mi][ni][r] + bb;
                if (dorelu) v = relu(v);
                if (C) C[row * N + col] = v;
                if (Cb) {
                    ushort_t hi = f2b(v);
                    Cb[row * cbld + col] = hi;
                    if (cblo) Cb[row * cbld + cblo + col] = f2b(v - bf2f(hi));
                }
            }
        }
    }
}

// Ehat[row] (width 864): [ sum_{j:adj=1} relu(hi_p+hj) hi (256) | deg | 0 |
//                          same lo (256) | 0 | same hi again (256) | deg | 0 ]
__global__ __launch_bounds__(256) void msg_kernel(
    const float* __restrict__ hcat,   // [1024][1280]: [hi_p | hj | gh]
    const int*   __restrict__ adj,    // [1024][256]
    ushort_t* __restrict__ ehat)      // [1024][864]
{
    const int row = blockIdx.x;
    const int t = threadIdx.x;
    __shared__ int ej[256];
    __shared__ int ecnt;
    if (t == 0) ecnt = 0;
    __syncthreads();
    if (adj[row * 256 + t]) { int p = atomicAdd(&ecnt, 1); ej[p] = t; }
    const float hi = hcat[row * 1280 + t];
    const float* hjb = hcat + (row >> 8) * 256 * 1280 + 256;
    __syncthreads();
    const int ne = ecnt;
    float acc = 0.f;
#pragma unroll 4
    for (int p = 0; p < ne; ++p) {
        int j = ej[p];
        acc += relu(hi + hjb[j * 1280 + t]);
    }
    ushort_t h16 = f2b(acc);
    ushort_t l16 = f2b(acc - bf2f(h16));
    ehat[row * 864 + t] = h16;
    ehat[row * 864 + 288 + t] = l16;
    ehat[row * 864 + 576 + t] = h16;
    if (t < 32) {
        ushort_t d = f2b(t == 0 ? (float)ne : 0.f);  // deg exact (<=256)
        ehat[row * 864 + 256 + t] = d;
        ehat[row * 864 + 544 + t] = 0;
        ehat[row * 864 + 832 + t] = d;
    }
}

__global__ __launch_bounds__(256) void gru_kernel(
    const float* __restrict__ gi,     // [1024][768]
    const float* __restrict__ hcat,   // gh at col 512
    float* __restrict__ h,            // fp32 h (in/out)
    ushort_t* __restrict__ h2)        // bf16 h hi|lo [1024][512]
{
    const int row = blockIdx.x;
    const int t = threadIdx.x;
    const float* gir = gi + row * 768;
    const float* ghr = hcat + row * 1280 + 512;
    float ir = gir[t], iz = gir[256 + t], in = gir[512 + t];
    float hr = ghr[t], hz = ghr[256 + t], hn = ghr[512 + t];
    float r = 1.f / (1.f + __expf(-(ir + hr)));
    float z = 1.f / (1.f + __expf(-(iz + hz)));
    float n = tanhf(in + r * hn);
    float ho = h[row * 256 + t];
    float hv = (1.f - z) * n + z * ho;
    h[row * 256 + t] = hv;
    ushort_t hb = f2b(hv);
    h2[row * 512 + t] = hb;
    h2[row * 512 + 256 + t] = f2b(hv - bf2f(hb));
}

__global__ __launch_bounds__(256) void readout_kernel(
    const float* __restrict__ h,
    const float* __restrict__ roW1, const float* __restrict__ rob1,
    const float* __restrict__ roW2, const float* __restrict__ rob2,
    void* __restrict__ out, const int* __restrict__ flagp)
{
    const int b = blockIdx.x;
    const int t = threadIdx.x;
    __shared__ float gl[256], t1[256];
    const float* hb = h + b * 256 * 256;
    float s = 0.f;
    for (int n = 0; n < 256; ++n) s += hb[n * 256 + t];
    gl[t] = s;
    __syncthreads();
    float acc = rob1[t];
    for (int k = 0; k < 256; ++k) acc += gl[k] * roW1[k * 256 + t];
    t1[t] = relu(acc);
    __syncthreads();
    if (t < 16) {
        float q = rob2[t];
        for (int k = 0; k < 256; ++k) q += t1[k] * roW2[k * 16 + t];
        if (*flagp) ((float*)out)[b * 16 + t] = q;
        else ((__hip_bfloat16*)out)[b * 16 + t] = __float2bfloat16(q);
    }
}

extern "C" void kernel_launch(void* const* d_in, const int* in_sizes, int n_in,
                              void* d_out, int out_size, void* d_ws, size_t ws_size,
                              hipStream_t stream) {
    float* w = (float*)d_ws;
    ushort_t* wb = (ushort_t*)d_ws;
    int* flagp = (int*)(w + F_FLAG);

    static const int dictSz[18]  = {65536,262144,16384,256,65536,256,131072,256,65536,256,
                                    196608,196608,768,768,65536,256,4096,16};
    static const int alphaSz[18] = {262144,196608,196608,768,768,131072,65536,256,256,
                                    65536,16384,65536,256,256,65536,4096,256,16};
    static const int alphaPos[18] = {9,0,10,12,11,13,5,7,6,8,2,1,4,3,14,16,15,17};
    bool dictOK = true, alphaOK = true;
    for (int i = 0; i < 18 && i < n_in; ++i) {
        if (in_sizes[i] != dictSz[i])  dictOK = false;
        if (in_sizes[i] != alphaSz[i]) alphaOK = false;
    }
    const void* P[18];
    for (int l = 0; l < 18; ++l) P[l] = d_in[(!dictOK && alphaOK) ? alphaPos[l] : l];
    const int* adj = (const int*)P[1];

    detect_kernel<<<1, 256, 0, stream>>>((const ushort_t*)P[0], flagp);
    convert_kernel<<<(CV_TOTAL + 255) / 256, 256, 0, stream>>>(
        P[0], P[2], P[3], P[4], P[5], P[6], P[7], P[8], P[9],
        P[10], P[11], P[12], P[13], P[14], P[15], P[16], P[17], w, flagp);
    // Wg = W2hat . Wih  (fp32 accumulate over exact-bf16 weights, split hi/lo)
    wg_kernel<<<dim3(3, 72), 256, 0, stream>>>(P[8], P[9], P[10], wb + UB_WGT, flagp);

    // pre-net: X = relu(NF@preW1+b1) -> bf16 single; h = X@preW2+b2 -> fp32 + hi/lo
    mgemm_k<64><<<dim3(2, 16), 256, 0, stream>>>(
        wb + UB_NFB, wb + UB_PW1T, w + F_PREB1, (float*)nullptr,
        wb + UB_XB, 256, 0, 64, 256, 1);
    mgemm_k<64><<<dim3(2, 16), 256, 0, stream>>>(
        wb + UB_XB, wb + UB_PW2T, w + F_PREB2, w + F_H,
        wb + UB_H2, 512, 256, 256, 256, 0);

    for (int it = 0; it < 3; ++it) {
        // hcat = h @ [W1_i|W1_j|Whh] + [b1|0|bhh]   (A = h hi|lo, K=512)
        mgemm_k<64><<<dim3(10, 16), 256, 0, stream>>>(
            wb + UB_H2, wb + UB_WCATT, w + F_BCAT, w + F_HCAT,
            (ushort_t*)nullptr, 0, 0, 512, 1280, 0);
        msg_kernel<<<BN_ROWS, 256, 0, stream>>>(w + F_HCAT, adj, wb + UB_EHAT2);
        // gi = Ehat @ Wg + bih  (A = Ehat [Eh|El|Eh], K=864; deg col folds msg_b2)
        mgemm_k<64><<<dim3(6, 16), 256, 0, stream>>>(
            wb + UB_EHAT2, wb + UB_WGT, w + F_BIH, w + F_GI,
            (ushort_t*)nullptr, 0, 0, 864, 768, 0);
        gru_kernel<<<BN_ROWS, 256, 0, stream>>>(w + F_GI, w + F_HCAT,
                                                w + F_H, wb + UB_H2);
    }

    readout_kernel<<<4, 256, 0, stream>>>(w + F_H, w + F_ROW1, w + F_ROB1,
                                          w + F_ROW2, w + F_ROB2, d_out, flagp);
}